// Round 14
// baseline (660.270 us; speedup 1.0000x reference)
//
#include <hip/hip_runtime.h>
#include <hip/hip_bf16.h>

#define N_NODES 6144
#define IN_F 256
#define N_HEADS 4
#define N_HID 64
#define JS 16
#define JLEN (N_NODES / JS)        // 384
#define NW (JLEN / 32)             // 12 mask words per chunk row
#define SM_STRIDE 14               // words/row; 8B-aligned u64 slots

typedef __attribute__((ext_vector_type(4))) float floatx4;
typedef _Float16 half2_t __attribute__((ext_vector_type(2)));
typedef _Float16 half8_t __attribute__((ext_vector_type(8)));
typedef __attribute__((ext_vector_type(4))) unsigned uint4_t;
typedef short short2v __attribute__((ext_vector_type(2)));

// ---------------- Kernel 1: ht = h @ W (fp32); epilogue -> htF (f16 MFMA B-fragment layout),
//   srcv (f32), tE1pk/tE2pk = f16x2 pairs of exp(tgt), exp(0.2*tgt).
__global__ __launch_bounds__(256) void ht_gemm_kernel(
    const float* __restrict__ h, const float* __restrict__ W,
    const float* __restrict__ a, short* __restrict__ htF,
    float* __restrict__ srcv, unsigned* __restrict__ tE1pk, unsigned* __restrict__ tE2pk)
{
    __shared__ float As[32][34];
    __shared__ float Bs[32][68];
    __shared__ float redS[32][16];
    __shared__ float redT[32][16];
    __shared__ unsigned short eh1[32], eh2[32];

    const int head = blockIdx.y;
    const int i0 = blockIdx.x * 32;
    const int tid = threadIdx.x;
    const int tx = tid & 15, ty = tid >> 4;

    float acc[2][4] = {};

    for (int k0 = 0; k0 < IN_F; k0 += 32) {
        __syncthreads();
        {
            const int m = tid >> 3, kq = tid & 7;
            const float4 v = *(const float4*)(h + (i0 + m) * IN_F + k0 + kq * 4);
            As[kq*4+0][m] = v.x; As[kq*4+1][m] = v.y;
            As[kq*4+2][m] = v.z; As[kq*4+3][m] = v.w;
        }
        #pragma unroll
        for (int it = 0; it < 2; ++it) {
            int l = it * 256 + tid;
            int k = l >> 4, nq = l & 15;
            *(float4*)&Bs[k][nq*4] = *(const float4*)(W + (k0 + k) * 256 + head * 64 + nq * 4);
        }
        __syncthreads();
        #pragma unroll
        for (int kk = 0; kk < 32; ++kk) {
            const float2 av = *(const float2*)&As[kk][ty*2];
            const float4 bv = *(const float4*)&Bs[kk][tx*4];
            const float aa[2] = {av.x, av.y};
            const float bb[4] = {bv.x, bv.y, bv.z, bv.w};
            #pragma unroll
            for (int r = 0; r < 2; ++r)
                #pragma unroll
                for (int c = 0; c < 4; ++c)
                    acc[r][c] = fmaf(aa[r], bb[c], acc[r][c]);
        }
    }

    #pragma unroll
    for (int r = 0; r < 2; ++r)
        #pragma unroll
        for (int c2 = 0; c2 < 4; ++c2) {
            const int d = tx * 4 + c2;
            const int j = i0 + ty * 2 + r;
            const int jt = j >> 5, q = (j >> 3) & 3, u = j & 7;
            const int c = d >> 4, n = d & 15;
            const size_t F = (((((size_t)head * 192 + jt) * 4 + c) * 16 + n) * 4 + q) * 8 + u;
            const _Float16 hv = (_Float16)acc[r][c2];
            htF[F] = *(const short*)&hv;
        }

    float as_[4], at_[4];
    #pragma unroll
    for (int c = 0; c < 4; ++c) {
        as_[c] = a[head * 128 + tx * 4 + c];
        at_[c] = a[head * 128 + 64 + tx * 4 + c];
    }
    #pragma unroll
    for (int r = 0; r < 2; ++r) {
        float ps = 0.f, pt = 0.f;
        #pragma unroll
        for (int c = 0; c < 4; ++c) {
            ps = fmaf(acc[r][c], as_[c], ps);
            pt = fmaf(acc[r][c], at_[c], pt);
        }
        redS[ty*2+r][tx] = ps;
        redT[ty*2+r][tx] = pt;
    }
    __syncthreads();
    if (tid < 64) {
        const int row = tid & 31;
        const float* src = (tid < 32) ? &redS[row][0] : &redT[row][0];
        float s = 0.f;
        #pragma unroll
        for (int x = 0; x < 16; ++x) s += src[x];
        if (tid < 32) {
            srcv[head * N_NODES + i0 + row] = s;
        } else {
            const _Float16 E1 = (_Float16)__expf(s);
            const _Float16 E2 = (_Float16)__expf(0.2f * s);
            eh1[row] = *(const unsigned short*)&E1;
            eh2[row] = *(const unsigned short*)&E2;
        }
    }
    __syncthreads();
    if (tid < 16) {
        const unsigned v1 = (unsigned)eh1[2*tid] | ((unsigned)eh1[2*tid+1] << 16);
        const unsigned v2 = (unsigned)eh2[2*tid] | ((unsigned)eh2[2*tid+1] << 16);
        tE1pk[head * (N_NODES/2) + i0/2 + tid] = v1;
        tE2pk[head * (N_NODES/2) + i0/2 + tid] = v2;
    }
}

// ---------------- Kernel 2: fused adj-pack (dense ballot staging) + masked softmax + PV.
// JS=16 -> 1536 blocks = 6 blocks/CU = 24 waves/CU (grid was the occupancy limiter).
// 1D grid, XCD swizzle. block = (64,4): wave y = head y; 64 rows/wave.
__global__ __launch_bounds__(256, 6) void gat_main_kernel(
    const int* __restrict__ adj, const short* __restrict__ htF,
    const float* __restrict__ srcv, const unsigned* __restrict__ tE1pk,
    const unsigned* __restrict__ tE2pk,
    float* __restrict__ pnum, float* __restrict__ pden)
{
    __shared__ unsigned smask[64 * SM_STRIDE];       // 3.6 KB
    __shared__ unsigned sE1[4 * 192], sE2[4 * 192];  // 6 KB: E for all 4 heads of this jc

    const int bid = blockIdx.x;
    const int xcd = bid & 7;
    const int idx = bid >> 3;
    const int jc = idx / 12;                         // 0..15
    const int rb0 = ((idx % 12) * 8 + xcd) * 64;     // 0..6080

    const int lane = threadIdx.x;
    const int head = threadIdx.y;                    // wave = head
    const int m = lane & 15, quad = lane >> 4;
    const int jbase = jc * JLEN;
    const int tid = head * 64 + lane;

    // ---- dense staging + ballot pack: 384 (row, W64) items, 96 per wave, 8-way unrolled
    const int* adjb = adj + (size_t)rb0 * N_NODES + jbase + lane;
    for (int k0 = 0; k0 < 96; k0 += 8) {
        int v[8];
        #pragma unroll
        for (int s = 0; s < 8; ++s) {
            const int f = (k0 + s) * 4 + head;       // 0..383
            const int r = f / 6, W = f % 6;          // 6 groups of 64 j per row
            v[s] = adjb[(size_t)r * N_NODES + W * 64];
        }
        #pragma unroll
        for (int s = 0; s < 8; ++s) {
            const unsigned long long b = __ballot(v[s] > 0);
            const int f = (k0 + s) * 4 + head;
            const int r = f / 6, W = f % 6;
            if (lane == 0)
                *(unsigned long long*)&smask[r * SM_STRIDE + 2 * W] = b;
        }
    }
    // stage E1/E2 for all 4 heads of this jc: 384 uint4 total
    #pragma unroll
    for (int it = 0; it < 2; ++it) {
        const int flat = it * 256 + tid;             // 0..511, valid < 384
        if (flat < 384) {
            const int isE2 = flat >= 192;
            const int f = isE2 ? flat - 192 : flat;  // 0..191
            const int hh = f / 48, w4 = f % 48;
            const unsigned* g = (isE2 ? tE2pk : tE1pk) + hh * (N_NODES/2) + (jbase >> 1) + w4 * 4;
            const uint4_t v = *(const uint4_t*)g;
            unsigned* dst = (isE2 ? sE2 : sE1) + hh * 192 + w4 * 4;
            dst[0] = v.x; dst[1] = v.y; dst[2] = v.z; dst[3] = v.w;
        }
    }
    __syncthreads();

    half2_t e1s[4], e2s[4];
    #pragma unroll
    for (int t = 0; t < 4; ++t) {
        const float sv = srcv[head * N_NODES + rb0 + t * 16 + m];
        const _Float16 a1 = (_Float16)__expf(sv);
        const _Float16 a2 = (_Float16)__expf(0.2f * sv);
        e1s[t] = (half2_t){a1, a1};
        e2s[t] = (half2_t){a2, a2};
    }

    const short* fb = htF + ((size_t)(head * 192 + (jbase >> 5)) * 4) * 512 + (m * 4 + quad) * 8;
    const unsigned* mrow = &smask[m * SM_STRIDE];   // tile t adds t*16*SM_STRIDE
    const unsigned* pe1 = &sE1[head * 192];
    const unsigned* pe2 = &sE2[head * 192];

    half8_t bones;
    #pragma unroll
    for (int u = 0; u < 8; ++u) bones[u] = (_Float16)1.0f;

    floatx4 accN[4][4];
    floatx4 accD[4];
    #pragma unroll
    for (int t = 0; t < 4; ++t) {
        accD[t] = (floatx4){0,0,0,0};
        #pragma unroll
        for (int c = 0; c < 4; ++c) accN[t][c] = (floatx4){0,0,0,0};
    }

    // depth-1 prefetch of b-fragments
    half8_t bn[4];
    #pragma unroll
    for (int c = 0; c < 4; ++c) bn[c] = *(const half8_t*)(fb + c * 512);

    for (int w = 0; w < NW; ++w) {
        half8_t bc[4];
        #pragma unroll
        for (int c = 0; c < 4; ++c) bc[c] = bn[c];
        const int wn = (w + 1 < NW) ? (w + 1) : w;      // clamped prefetch
        #pragma unroll
        for (int c = 0; c < 4; ++c)
            bn[c] = *(const half8_t*)(fb + (size_t)wn * 2048 + c * 512);

        const uint4_t E1 = *(const uint4_t*)(pe1 + w * 16 + quad * 4);   // ds_read_b128
        const uint4_t E2 = *(const uint4_t*)(pe2 + w * 16 + quad * 4);
        const unsigned E1a[4] = {E1.x, E1.y, E1.z, E1.w};
        const unsigned E2a[4] = {E2.x, E2.y, E2.z, E2.w};

        #pragma unroll
        for (int t = 0; t < 4; ++t) {
            const unsigned bits = (mrow[t * (16*SM_STRIDE) + w] >> (quad * 8)) & 0xffu;
            const short2v tt = __builtin_bit_cast(short2v, bits * 0x10001u);
            uint4_t af_u;
            #pragma unroll
            for (int p = 0; p < 4; ++p) {
                const short2v shl = (p == 0) ? (short2v){15,14} : (p == 1) ? (short2v){13,12}
                                 : (p == 2) ? (short2v){11,10} : (short2v){9,8};
                const short2v k = (tt << shl) >> (short2v){15,15};   // 0xFFFF/0x0000 per half
                const half2_t p1 = __builtin_bit_cast(half2_t, E1a[p]) * e1s[t];
                const half2_t p2 = __builtin_bit_cast(half2_t, E2a[p]) * e2s[t];
                const half2_t mx = __builtin_elementwise_max(p1, p2); // exp(lrelu) = max of exps
                const unsigned r = __builtin_bit_cast(unsigned, mx) & __builtin_bit_cast(unsigned, k);
                if (p == 0) af_u.x = r; else if (p == 1) af_u.y = r;
                else if (p == 2) af_u.z = r; else af_u.w = r;
            }
            const half8_t af = __builtin_bit_cast(half8_t, af_u);
            #pragma unroll
            for (int c = 0; c < 4; ++c)
                accN[t][c] = __builtin_amdgcn_mfma_f32_16x16x32_f16(af, bc[c], accN[t][c], 0, 0, 0);
            accD[t] = __builtin_amdgcn_mfma_f32_16x16x32_f16(af, bones, accD[t], 0, 0, 0);
        }
    }

    const int slot = jc * N_HEADS + head;
    #pragma unroll
    for (int t = 0; t < 4; ++t) {
        if (m == 0) {
            #pragma unroll
            for (int r = 0; r < 4; ++r)
                pden[slot * N_NODES + rb0 + t * 16 + quad * 4 + r] = accD[t][r];
        }
        #pragma unroll
        for (int r = 0; r < 4; ++r) {
            const int gi = rb0 + t * 16 + quad * 4 + r;
            float* np_ = pnum + ((size_t)slot * N_NODES + gi) * N_HID + m;
            np_[0]  = accN[t][0][r];
            np_[16] = accN[t][1][r];
            np_[32] = accN[t][2][r];
            np_[48] = accN[t][3][r];
        }
    }
}

// ---------------- Kernel 3: reduce j-chunks, divide, mean over heads (float4)
__global__ __launch_bounds__(256) void finalize_kernel(
    const float* __restrict__ pnum, const float* __restrict__ pden,
    float* __restrict__ out)
{
    const int idx = blockIdx.x * 256 + threadIdx.x;   // over N_NODES*16
    if (idx >= N_NODES * 16) return;
    const int i = idx >> 4;
    const int d4 = (idx & 15) * 4;
    float sx = 0.f, sy = 0.f, sz = 0.f, sw = 0.f;
    #pragma unroll
    for (int hh = 0; hh < N_HEADS; ++hh) {
        float nx = 0.f, ny = 0.f, nz = 0.f, nw_ = 0.f, ds = 0.f;
        for (int jc = 0; jc < JS; ++jc) {
            const int slot = jc * N_HEADS + hh;
            const float4 v = *(const float4*)(pnum + ((size_t)slot * N_NODES + i) * N_HID + d4);
            nx += v.x; ny += v.y; nz += v.z; nw_ += v.w;
            ds += pden[slot * N_NODES + i];
        }
        const float r = 1.0f / ds;
        sx += nx * r; sy += ny * r; sz += nz * r; sw += nw_ * r;
    }
    float4 o; o.x = 0.25f * sx; o.y = 0.25f * sy; o.z = 0.25f * sz; o.w = 0.25f * sw;
    *(float4*)(out + (size_t)i * N_HID + d4) = o;
}

extern "C" void kernel_launch(void* const* d_in, const int* in_sizes, int n_in,
                              void* d_out, int out_size, void* d_ws, size_t ws_size,
                              hipStream_t stream)
{
    const float* h   = (const float*)d_in[0];
    const int*   adj = (const int*)d_in[1];
    const float* W   = (const float*)d_in[2];
    const float* a   = (const float*)d_in[3];
    float* out = (float*)d_out;

    char* ws = (char*)d_ws;
    short* htF = (short*)ws;
    size_t off = (size_t)N_HEADS * N_HID * N_NODES * 2;              // 3.1 MB
    float* srcv = (float*)(ws + off);        off += (size_t)N_HEADS * N_NODES * 4;
    unsigned* tE1pk = (unsigned*)(ws + off); off += (size_t)N_HEADS * (N_NODES/2) * 4;
    unsigned* tE2pk = (unsigned*)(ws + off); off += (size_t)N_HEADS * (N_NODES/2) * 4;
    float* pnum = (float*)(ws + off);        off += (size_t)JS * N_HEADS * N_NODES * N_HID * 4;  // 100.7 MB
    float* pden = (float*)(ws + off);

    ht_gemm_kernel<<<dim3(N_NODES / 32, N_HEADS), 256, 0, stream>>>(h, W, a, htF, srcv, tE1pk, tE2pk);
    gat_main_kernel<<<1536, dim3(64, 4), 0, stream>>>(
        adj, htF, srcv, tE1pk, tE2pk, pnum, pden);
    finalize_kernel<<<dim3((N_NODES * 16 + 255) / 256), 256, 0, stream>>>(pnum, pden, out);
}

// Round 15
// 273.647 us; speedup vs baseline: 2.4129x; 2.4129x over previous
//
#include <hip/hip_runtime.h>
#include <hip/hip_bf16.h>

#define N_NODES 6144
#define IN_F 256
#define N_HEADS 4
#define N_HID 64
#define JS 8
#define JLEN (N_NODES / JS)        // 768
#define NW (JLEN / 32)             // 24 mask words per chunk row
#define SM_STRIDE 28               // words/row; 8B-aligned u64 slots; 2-way bank alias only

typedef __attribute__((ext_vector_type(4))) float floatx4;
typedef _Float16 half2_t __attribute__((ext_vector_type(2)));
typedef _Float16 half8_t __attribute__((ext_vector_type(8)));
typedef __attribute__((ext_vector_type(4))) unsigned uint4_t;
typedef short short2v __attribute__((ext_vector_type(2)));

// ---------------- Kernel 1: ht = h @ W (fp32); epilogue -> htF (f16 MFMA B-fragment layout),
//   srcv (f32), tE1pk/tE2pk = f16x2 pairs of exp(tgt), exp(0.2*tgt).
__global__ __launch_bounds__(256) void ht_gemm_kernel(
    const float* __restrict__ h, const float* __restrict__ W,
    const float* __restrict__ a, short* __restrict__ htF,
    float* __restrict__ srcv, unsigned* __restrict__ tE1pk, unsigned* __restrict__ tE2pk)
{
    __shared__ float As[32][34];
    __shared__ float Bs[32][68];
    __shared__ float redS[32][16];
    __shared__ float redT[32][16];
    __shared__ unsigned short eh1[32], eh2[32];

    const int head = blockIdx.y;
    const int i0 = blockIdx.x * 32;
    const int tid = threadIdx.x;
    const int tx = tid & 15, ty = tid >> 4;

    float acc[2][4] = {};

    for (int k0 = 0; k0 < IN_F; k0 += 32) {
        __syncthreads();
        {
            const int m = tid >> 3, kq = tid & 7;
            const float4 v = *(const float4*)(h + (i0 + m) * IN_F + k0 + kq * 4);
            As[kq*4+0][m] = v.x; As[kq*4+1][m] = v.y;
            As[kq*4+2][m] = v.z; As[kq*4+3][m] = v.w;
        }
        #pragma unroll
        for (int it = 0; it < 2; ++it) {
            int l = it * 256 + tid;
            int k = l >> 4, nq = l & 15;
            *(float4*)&Bs[k][nq*4] = *(const float4*)(W + (k0 + k) * 256 + head * 64 + nq * 4);
        }
        __syncthreads();
        #pragma unroll
        for (int kk = 0; kk < 32; ++kk) {
            const float2 av = *(const float2*)&As[kk][ty*2];
            const float4 bv = *(const float4*)&Bs[kk][tx*4];
            const float aa[2] = {av.x, av.y};
            const float bb[4] = {bv.x, bv.y, bv.z, bv.w};
            #pragma unroll
            for (int r = 0; r < 2; ++r)
                #pragma unroll
                for (int c = 0; c < 4; ++c)
                    acc[r][c] = fmaf(aa[r], bb[c], acc[r][c]);
        }
    }

    #pragma unroll
    for (int r = 0; r < 2; ++r)
        #pragma unroll
        for (int c2 = 0; c2 < 4; ++c2) {
            const int d = tx * 4 + c2;
            const int j = i0 + ty * 2 + r;
            const int jt = j >> 5, q = (j >> 3) & 3, u = j & 7;
            const int c = d >> 4, n = d & 15;
            const size_t F = (((((size_t)head * 192 + jt) * 4 + c) * 16 + n) * 4 + q) * 8 + u;
            const _Float16 hv = (_Float16)acc[r][c2];
            htF[F] = *(const short*)&hv;
        }

    float as_[4], at_[4];
    #pragma unroll
    for (int c = 0; c < 4; ++c) {
        as_[c] = a[head * 128 + tx * 4 + c];
        at_[c] = a[head * 128 + 64 + tx * 4 + c];
    }
    #pragma unroll
    for (int r = 0; r < 2; ++r) {
        float ps = 0.f, pt = 0.f;
        #pragma unroll
        for (int c = 0; c < 4; ++c) {
            ps = fmaf(acc[r][c], as_[c], ps);
            pt = fmaf(acc[r][c], at_[c], pt);
        }
        redS[ty*2+r][tx] = ps;
        redT[ty*2+r][tx] = pt;
    }
    __syncthreads();
    if (tid < 64) {
        const int row = tid & 31;
        const float* src = (tid < 32) ? &redS[row][0] : &redT[row][0];
        float s = 0.f;
        #pragma unroll
        for (int x = 0; x < 16; ++x) s += src[x];
        if (tid < 32) {
            srcv[head * N_NODES + i0 + row] = s;
        } else {
            const _Float16 E1 = (_Float16)__expf(s);
            const _Float16 E2 = (_Float16)__expf(0.2f * s);
            eh1[row] = *(const unsigned short*)&E1;
            eh2[row] = *(const unsigned short*)&E2;
        }
    }
    __syncthreads();
    if (tid < 16) {
        const unsigned v1 = (unsigned)eh1[2*tid] | ((unsigned)eh1[2*tid+1] << 16);
        const unsigned v2 = (unsigned)eh2[2*tid] | ((unsigned)eh2[2*tid+1] << 16);
        tE1pk[head * (N_NODES/2) + i0/2 + tid] = v1;
        tE2pk[head * (N_NODES/2) + i0/2 + tid] = v2;
    }
}

// ---------------- Kernel 2: fused adj-pack (dense ballot staging) + masked softmax + PV.
// R12 base (JS=8, 768 blocks, launch_bounds(256,3) -- do NOT raise: unified VGPR+AGPR
// file needs ~160 regs; (256,6) caps at 85 and spills accumulators (R13: 2GB scratch).
// New in R14: depth-1 prefetch extended to the in-loop LDS reads (E1/E2 b128, mask b32x4).
__global__ __launch_bounds__(256, 3) void gat_main_kernel(
    const int* __restrict__ adj, const short* __restrict__ htF,
    const float* __restrict__ srcv, const unsigned* __restrict__ tE1pk,
    const unsigned* __restrict__ tE2pk,
    float* __restrict__ pnum, float* __restrict__ pden)
{
    __shared__ unsigned smask[64 * SM_STRIDE];       // 7.2 KB
    __shared__ unsigned sE1[4 * 384], sE2[4 * 384];  // 12 KB: E for all 4 heads of this jc

    const int bid = blockIdx.x;
    const int xcd = bid & 7;
    const int idx = bid >> 3;
    const int jc = idx / 12;
    const int rb0 = ((idx % 12) * 8 + xcd) * 64;

    const int lane = threadIdx.x;
    const int head = threadIdx.y;                // wave = head
    const int m = lane & 15, quad = lane >> 4;
    const int jbase = jc * JLEN;
    const int tid = head * 64 + lane;

    // ---- dense staging + ballot pack: 768 (row, W64) items, 192 per wave, 8-way unrolled
    const int* adjb = adj + (size_t)rb0 * N_NODES + jbase + lane;
    for (int k0 = 0; k0 < 192; k0 += 8) {
        int v[8];
        #pragma unroll
        for (int s = 0; s < 8; ++s) {
            const int f = (k0 + s) * 4 + head;   // 0..767
            const int r = f / 12, W = f % 12;    // 12 groups of 64 j per row
            v[s] = adjb[(size_t)r * N_NODES + W * 64];
        }
        #pragma unroll
        for (int s = 0; s < 8; ++s) {
            const unsigned long long b = __ballot(v[s] > 0);
            const int f = (k0 + s) * 4 + head;
            const int r = f / 12, W = f % 12;
            if (lane == 0)
                *(unsigned long long*)&smask[r * SM_STRIDE + 2 * W] = b;
        }
    }
    // stage E1/E2 for all 4 heads of this jc: 768 uint4, 3 per thread
    #pragma unroll
    for (int it = 0; it < 3; ++it) {
        const int flat = it * 256 + tid;         // 0..767
        const int isE2 = flat >= 384;
        const int f = isE2 ? flat - 384 : flat;  // 0..383
        const int hh = f / 96, w4 = f % 96;
        const unsigned* g = (isE2 ? tE2pk : tE1pk) + hh * (N_NODES/2) + (jbase >> 1) + w4 * 4;
        const uint4_t v = *(const uint4_t*)g;
        unsigned* dst = (isE2 ? sE2 : sE1) + hh * 384 + w4 * 4;
        dst[0] = v.x; dst[1] = v.y; dst[2] = v.z; dst[3] = v.w;
    }
    __syncthreads();

    half2_t e1s[4], e2s[4];
    #pragma unroll
    for (int t = 0; t < 4; ++t) {
        const float sv = srcv[head * N_NODES + rb0 + t * 16 + m];
        const _Float16 a1 = (_Float16)__expf(sv);
        const _Float16 a2 = (_Float16)__expf(0.2f * sv);
        e1s[t] = (half2_t){a1, a1};
        e2s[t] = (half2_t){a2, a2};
    }

    const short* fb = htF + ((size_t)(head * 192 + (jbase >> 5)) * 4) * 512 + (m * 4 + quad) * 8;
    const unsigned* mrow = &smask[m * SM_STRIDE];   // tile t adds t*16*SM_STRIDE
    const unsigned* pe1 = &sE1[head * 384];
    const unsigned* pe2 = &sE2[head * 384];

    half8_t bones;
    #pragma unroll
    for (int u = 0; u < 8; ++u) bones[u] = (_Float16)1.0f;

    floatx4 accN[4][4];
    floatx4 accD[4];
    #pragma unroll
    for (int t = 0; t < 4; ++t) {
        accD[t] = (floatx4){0,0,0,0};
        #pragma unroll
        for (int c = 0; c < 4; ++c) accN[t][c] = (floatx4){0,0,0,0};
    }

    // depth-1 prefetch: b-fragments (global) + E (LDS b128) + mask words (LDS b32 x4)
    half8_t bn[4];
    #pragma unroll
    for (int c = 0; c < 4; ++c) bn[c] = *(const half8_t*)(fb + c * 512);
    uint4_t E1n = *(const uint4_t*)(pe1 + quad * 4);
    uint4_t E2n = *(const uint4_t*)(pe2 + quad * 4);
    unsigned mqn[4];
    #pragma unroll
    for (int t = 0; t < 4; ++t) mqn[t] = mrow[t * (16*SM_STRIDE)];

    for (int w = 0; w < NW; ++w) {
        half8_t bc[4];
        #pragma unroll
        for (int c = 0; c < 4; ++c) bc[c] = bn[c];
        const uint4_t E1 = E1n, E2 = E2n;
        unsigned mq[4];
        #pragma unroll
        for (int t = 0; t < 4; ++t) mq[t] = mqn[t];

        const int wn = (w + 1 < NW) ? (w + 1) : w;      // clamped prefetch
        #pragma unroll
        for (int c = 0; c < 4; ++c)
            bn[c] = *(const half8_t*)(fb + (size_t)wn * 2048 + c * 512);
        E1n = *(const uint4_t*)(pe1 + wn * 16 + quad * 4);
        E2n = *(const uint4_t*)(pe2 + wn * 16 + quad * 4);
        #pragma unroll
        for (int t = 0; t < 4; ++t) mqn[t] = mrow[t * (16*SM_STRIDE) + wn];

        const unsigned E1a[4] = {E1.x, E1.y, E1.z, E1.w};
        const unsigned E2a[4] = {E2.x, E2.y, E2.z, E2.w};

        #pragma unroll
        for (int t = 0; t < 4; ++t) {
            const unsigned bits = (mq[t] >> (quad * 8)) & 0xffu;
            const short2v tt = __builtin_bit_cast(short2v, bits * 0x10001u);
            uint4_t af_u;
            #pragma unroll
            for (int p = 0; p < 4; ++p) {
                const short2v shl = (p == 0) ? (short2v){15,14} : (p == 1) ? (short2v){13,12}
                                 : (p == 2) ? (short2v){11,10} : (short2v){9,8};
                const short2v k = (tt << shl) >> (short2v){15,15};   // 0xFFFF/0x0000 per half
                const half2_t p1 = __builtin_bit_cast(half2_t, E1a[p]) * e1s[t];
                const half2_t p2 = __builtin_bit_cast(half2_t, E2a[p]) * e2s[t];
                const half2_t mx = __builtin_elementwise_max(p1, p2); // exp(lrelu) = max of exps
                const unsigned r = __builtin_bit_cast(unsigned, mx) & __builtin_bit_cast(unsigned, k);
                if (p == 0) af_u.x = r; else if (p == 1) af_u.y = r;
                else if (p == 2) af_u.z = r; else af_u.w = r;
            }
            const half8_t af = __builtin_bit_cast(half8_t, af_u);
            #pragma unroll
            for (int c = 0; c < 4; ++c)
                accN[t][c] = __builtin_amdgcn_mfma_f32_16x16x32_f16(af, bc[c], accN[t][c], 0, 0, 0);
            accD[t] = __builtin_amdgcn_mfma_f32_16x16x32_f16(af, bones, accD[t], 0, 0, 0);
        }
    }

    const int slot = jc * N_HEADS + head;
    #pragma unroll
    for (int t = 0; t < 4; ++t) {
        if (m == 0) {
            #pragma unroll
            for (int r = 0; r < 4; ++r)
                pden[slot * N_NODES + rb0 + t * 16 + quad * 4 + r] = accD[t][r];
        }
        #pragma unroll
        for (int r = 0; r < 4; ++r) {
            const int gi = rb0 + t * 16 + quad * 4 + r;
            float* np_ = pnum + ((size_t)slot * N_NODES + gi) * N_HID + m;
            np_[0]  = accN[t][0][r];
            np_[16] = accN[t][1][r];
            np_[32] = accN[t][2][r];
            np_[48] = accN[t][3][r];
        }
    }
}

// ---------------- Kernel 3: reduce j-chunks, divide, mean over heads (float4)
__global__ __launch_bounds__(256) void finalize_kernel(
    const float* __restrict__ pnum, const float* __restrict__ pden,
    float* __restrict__ out)
{
    const int idx = blockIdx.x * 256 + threadIdx.x;   // over N_NODES*16
    if (idx >= N_NODES * 16) return;
    const int i = idx >> 4;
    const int d4 = (idx & 15) * 4;
    float sx = 0.f, sy = 0.f, sz = 0.f, sw = 0.f;
    #pragma unroll
    for (int hh = 0; hh < N_HEADS; ++hh) {
        float nx = 0.f, ny = 0.f, nz = 0.f, nw_ = 0.f, ds = 0.f;
        #pragma unroll
        for (int jc = 0; jc < JS; ++jc) {
            const int slot = jc * N_HEADS + hh;
            const float4 v = *(const float4*)(pnum + ((size_t)slot * N_NODES + i) * N_HID + d4);
            nx += v.x; ny += v.y; nz += v.z; nw_ += v.w;
            ds += pden[slot * N_NODES + i];
        }
        const float r = 1.0f / ds;
        sx += nx * r; sy += ny * r; sz += nz * r; sw += nw_ * r;
    }
    float4 o; o.x = 0.25f * sx; o.y = 0.25f * sy; o.z = 0.25f * sz; o.w = 0.25f * sw;
    *(float4*)(out + (size_t)i * N_HID + d4) = o;
}

extern "C" void kernel_launch(void* const* d_in, const int* in_sizes, int n_in,
                              void* d_out, int out_size, void* d_ws, size_t ws_size,
                              hipStream_t stream)
{
    const float* h   = (const float*)d_in[0];
    const int*   adj = (const int*)d_in[1];
    const float* W   = (const float*)d_in[2];
    const float* a   = (const float*)d_in[3];
    float* out = (float*)d_out;

    char* ws = (char*)d_ws;
    short* htF = (short*)ws;
    size_t off = (size_t)N_HEADS * N_HID * N_NODES * 2;              // 3.1 MB
    float* srcv = (float*)(ws + off);        off += (size_t)N_HEADS * N_NODES * 4;
    unsigned* tE1pk = (unsigned*)(ws + off); off += (size_t)N_HEADS * (N_NODES/2) * 4;
    unsigned* tE2pk = (unsigned*)(ws + off); off += (size_t)N_HEADS * (N_NODES/2) * 4;
    float* pnum = (float*)(ws + off);        off += (size_t)JS * N_HEADS * N_NODES * N_HID * 4;  // 50.3 MB
    float* pden = (float*)(ws + off);

    ht_gemm_kernel<<<dim3(N_NODES / 32, N_HEADS), 256, 0, stream>>>(h, W, a, htF, srcv, tE1pk, tE2pk);
    gat_main_kernel<<<768, dim3(64, 4), 0, stream>>>(
        adj, htF, srcv, tE1pk, tE2pk, pnum, pden);
    finalize_kernel<<<dim3((N_NODES * 16 + 255) / 256), 256, 0, stream>>>(pnum, pden, out);
}

// Round 16
// 271.421 us; speedup vs baseline: 2.4326x; 1.0082x over previous
//
#include <hip/hip_runtime.h>
#include <hip/hip_bf16.h>

#define N_NODES 6144
#define IN_F 256
#define N_HEADS 4
#define N_HID 64
#define JS 8
#define JLEN (N_NODES / JS)        // 768
#define NW (JLEN / 32)             // 24 iterations per chunk row
#define SMB 776                    // byte stride per row: 768 + 8 (u64-aligned)

typedef __attribute__((ext_vector_type(4))) float floatx4;
typedef _Float16 half2_t __attribute__((ext_vector_type(2)));
typedef _Float16 half8_t __attribute__((ext_vector_type(8)));
typedef __attribute__((ext_vector_type(4))) unsigned uint4_t;

// ---------------- Kernel 1: ht = h @ W (fp32); epilogue -> htF (f16 MFMA B-fragment layout),
//   srcv (f32), tE1pk/tE2pk = f16x2 pairs of exp(tgt), exp(0.2*tgt).
__global__ __launch_bounds__(256) void ht_gemm_kernel(
    const float* __restrict__ h, const float* __restrict__ W,
    const float* __restrict__ a, short* __restrict__ htF,
    float* __restrict__ srcv, unsigned* __restrict__ tE1pk, unsigned* __restrict__ tE2pk)
{
    __shared__ float As[32][34];
    __shared__ float Bs[32][68];
    __shared__ float redS[32][16];
    __shared__ float redT[32][16];
    __shared__ unsigned short eh1[32], eh2[32];

    const int head = blockIdx.y;
    const int i0 = blockIdx.x * 32;
    const int tid = threadIdx.x;
    const int tx = tid & 15, ty = tid >> 4;

    float acc[2][4] = {};

    for (int k0 = 0; k0 < IN_F; k0 += 32) {
        __syncthreads();
        {
            const int m = tid >> 3, kq = tid & 7;
            const float4 v = *(const float4*)(h + (i0 + m) * IN_F + k0 + kq * 4);
            As[kq*4+0][m] = v.x; As[kq*4+1][m] = v.y;
            As[kq*4+2][m] = v.z; As[kq*4+3][m] = v.w;
        }
        #pragma unroll
        for (int it = 0; it < 2; ++it) {
            int l = it * 256 + tid;
            int k = l >> 4, nq = l & 15;
            *(float4*)&Bs[k][nq*4] = *(const float4*)(W + (k0 + k) * 256 + head * 64 + nq * 4);
        }
        __syncthreads();
        #pragma unroll
        for (int kk = 0; kk < 32; ++kk) {
            const float2 av = *(const float2*)&As[kk][ty*2];
            const float4 bv = *(const float4*)&Bs[kk][tx*4];
            const float aa[2] = {av.x, av.y};
            const float bb[4] = {bv.x, bv.y, bv.z, bv.w};
            #pragma unroll
            for (int r = 0; r < 2; ++r)
                #pragma unroll
                for (int c = 0; c < 4; ++c)
                    acc[r][c] = fmaf(aa[r], bb[c], acc[r][c]);
        }
    }

    #pragma unroll
    for (int r = 0; r < 2; ++r)
        #pragma unroll
        for (int c2 = 0; c2 < 4; ++c2) {
            const int d = tx * 4 + c2;
            const int j = i0 + ty * 2 + r;
            const int jt = j >> 5, q = (j >> 3) & 3, u = j & 7;
            const int c = d >> 4, n = d & 15;
            const size_t F = (((((size_t)head * 192 + jt) * 4 + c) * 16 + n) * 4 + q) * 8 + u;
            const _Float16 hv = (_Float16)acc[r][c2];
            htF[F] = *(const short*)&hv;
        }

    float as_[4], at_[4];
    #pragma unroll
    for (int c = 0; c < 4; ++c) {
        as_[c] = a[head * 128 + tx * 4 + c];
        at_[c] = a[head * 128 + 64 + tx * 4 + c];
    }
    #pragma unroll
    for (int r = 0; r < 2; ++r) {
        float ps = 0.f, pt = 0.f;
        #pragma unroll
        for (int c = 0; c < 4; ++c) {
            ps = fmaf(acc[r][c], as_[c], ps);
            pt = fmaf(acc[r][c], at_[c], pt);
        }
        redS[ty*2+r][tx] = ps;
        redT[ty*2+r][tx] = pt;
    }
    __syncthreads();
    if (tid < 64) {
        const int row = tid & 31;
        const float* src = (tid < 32) ? &redS[row][0] : &redT[row][0];
        float s = 0.f;
        #pragma unroll
        for (int x = 0; x < 16; ++x) s += src[x];
        if (tid < 32) {
            srcv[head * N_NODES + i0 + row] = s;
        } else {
            const _Float16 E1 = (_Float16)__expf(s);
            const _Float16 E2 = (_Float16)__expf(0.2f * s);
            eh1[row] = *(const unsigned short*)&E1;
            eh2[row] = *(const unsigned short*)&E2;
        }
    }
    __syncthreads();
    if (tid < 16) {
        const unsigned v1 = (unsigned)eh1[2*tid] | ((unsigned)eh1[2*tid+1] << 16);
        const unsigned v2 = (unsigned)eh2[2*tid] | ((unsigned)eh2[2*tid+1] << 16);
        tE1pk[head * (N_NODES/2) + i0/2 + tid] = v1;
        tE2pk[head * (N_NODES/2) + i0/2 + tid] = v2;
    }
}

// ---------------- Kernel 2: fused adj->byte-mask + masked rank-1 softmax + PV.
// R12 base (JS=8, 768 blocks, XCD swizzle, launch_bounds(256,3) -- (256,6) spills: R13).
// R15: byte-mask LDS (dense int4 staging, *255 trick, no ballot) + v_perm mask expand
// (R5-verified selectors); E1/E2 global with depth-1 prefetch (LDS-E was neutral: R14).
__global__ __launch_bounds__(256, 3) void gat_main_kernel(
    const int* __restrict__ adj, const short* __restrict__ htF,
    const float* __restrict__ srcv, const unsigned* __restrict__ tE1pk,
    const unsigned* __restrict__ tE2pk,
    float* __restrict__ pnum, float* __restrict__ pden)
{
    __shared__ unsigned char smaskB[64 * SMB];   // 48.5 KB byte-mask (0x00/0xFF per j)

    const int bid = blockIdx.x;
    const int xcd = bid & 7;
    const int idx = bid >> 3;
    const int jc = idx / 12;
    const int rb0 = ((idx % 12) * 8 + xcd) * 64;

    const int lane = threadIdx.x;
    const int head = threadIdx.y;                // wave = head
    const int m = lane & 15, quad = lane >> 4;
    const int jbase = jc * JLEN;

    // ---- dense staging: item = (row r, 256-j group cg); lane l covers j = cg*256 + l*4..+3.
    // 192 wave-loads total (48/wave), each 1KB contiguous; byte-mask = (x|y<<8|z<<16|w<<24)*255.
    const int* adjb = adj + (size_t)rb0 * N_NODES + jbase + lane * 4;
    for (int k0 = 0; k0 < 48; k0 += 8) {
        int4 v[8];
        #pragma unroll
        for (int s = 0; s < 8; ++s) {
            const int item = (k0 + s) * 4 + head;    // 0..191
            const int r = item & 63, cg = item >> 6; // 64 rows x 3 groups
            v[s] = *(const int4*)(adjb + (size_t)r * N_NODES + cg * 256);
        }
        #pragma unroll
        for (int s = 0; s < 8; ++s) {
            const int item = (k0 + s) * 4 + head;
            const int r = item & 63, cg = item >> 6;
            const unsigned b = (unsigned)(v[s].x | (v[s].y << 8) | (v[s].z << 16) | (v[s].w << 24)) * 255u;
            *(unsigned*)(smaskB + r * SMB + cg * 256 + lane * 4) = b;
        }
    }
    __syncthreads();

    half2_t e1s[4], e2s[4];
    #pragma unroll
    for (int t = 0; t < 4; ++t) {
        const float sv = srcv[head * N_NODES + rb0 + t * 16 + m];
        const _Float16 a1 = (_Float16)__expf(sv);
        const _Float16 a2 = (_Float16)__expf(0.2f * sv);
        e1s[t] = (half2_t){a1, a1};
        e2s[t] = (half2_t){a2, a2};
    }

    const short* fb = htF + ((size_t)(head * 192 + (jbase >> 5)) * 4) * 512 + (m * 4 + quad) * 8;
    const unsigned char* mrow = smaskB + m * SMB + quad * 8;   // + t*16*SMB + w*32
    const unsigned* pe1 = tE1pk + head * (N_NODES/2) + (jbase >> 1);
    const unsigned* pe2 = tE2pk + head * (N_NODES/2) + (jbase >> 1);

    half8_t bones;
    #pragma unroll
    for (int u = 0; u < 8; ++u) bones[u] = (_Float16)1.0f;

    floatx4 accN[4][4];
    floatx4 accD[4];
    #pragma unroll
    for (int t = 0; t < 4; ++t) {
        accD[t] = (floatx4){0,0,0,0};
        #pragma unroll
        for (int c = 0; c < 4; ++c) accN[t][c] = (floatx4){0,0,0,0};
    }

    // depth-1 prefetch: b-fragments + E (global)
    half8_t bn[4];
    #pragma unroll
    for (int c = 0; c < 4; ++c) bn[c] = *(const half8_t*)(fb + c * 512);
    uint4_t E1n = *(const uint4_t*)(pe1 + quad * 4);
    uint4_t E2n = *(const uint4_t*)(pe2 + quad * 4);

    for (int w = 0; w < NW; ++w) {
        half8_t bc[4];
        #pragma unroll
        for (int c = 0; c < 4; ++c) bc[c] = bn[c];
        const uint4_t E1 = E1n, E2 = E2n;

        const int wn = (w + 1 < NW) ? (w + 1) : w;      // clamped prefetch
        #pragma unroll
        for (int c = 0; c < 4; ++c)
            bn[c] = *(const half8_t*)(fb + (size_t)wn * 2048 + c * 512);
        E1n = *(const uint4_t*)(pe1 + wn * 16 + quad * 4);
        E2n = *(const uint4_t*)(pe2 + wn * 16 + quad * 4);

        const unsigned E1a[4] = {E1.x, E1.y, E1.z, E1.w};
        const unsigned E2a[4] = {E2.x, E2.y, E2.z, E2.w};

        #pragma unroll
        for (int t = 0; t < 4; ++t) {
            // byte-mask u64 for this row-tile's 8 j; expand to halfword masks via v_perm
            const unsigned long long mB =
                *(const unsigned long long*)(mrow + t * (16*SMB) + w * 32);
            const unsigned mlo = (unsigned)mB, mhi = (unsigned)(mB >> 32);
            const unsigned k0 = __builtin_amdgcn_perm(0u, mlo, 0x01010000u);  // u0,u1
            const unsigned k1 = __builtin_amdgcn_perm(0u, mlo, 0x03030202u);  // u2,u3
            const unsigned k2 = __builtin_amdgcn_perm(0u, mhi, 0x01010000u);  // u4,u5
            const unsigned k3 = __builtin_amdgcn_perm(0u, mhi, 0x03030202u);  // u6,u7
            const unsigned ka[4] = {k0, k1, k2, k3};

            uint4_t af_u;
            #pragma unroll
            for (int p = 0; p < 4; ++p) {
                const half2_t p1 = __builtin_bit_cast(half2_t, E1a[p]) * e1s[t];
                const half2_t p2 = __builtin_bit_cast(half2_t, E2a[p]) * e2s[t];
                const half2_t mx = __builtin_elementwise_max(p1, p2); // exp(lrelu) = max of exps
                const unsigned r = __builtin_bit_cast(unsigned, mx) & ka[p];
                if (p == 0) af_u.x = r; else if (p == 1) af_u.y = r;
                else if (p == 2) af_u.z = r; else af_u.w = r;
            }
            const half8_t af = __builtin_bit_cast(half8_t, af_u);
            #pragma unroll
            for (int c = 0; c < 4; ++c)
                accN[t][c] = __builtin_amdgcn_mfma_f32_16x16x32_f16(af, bc[c], accN[t][c], 0, 0, 0);
            accD[t] = __builtin_amdgcn_mfma_f32_16x16x32_f16(af, bones, accD[t], 0, 0, 0);
        }
    }

    const int slot = jc * N_HEADS + head;
    #pragma unroll
    for (int t = 0; t < 4; ++t) {
        if (m == 0) {
            #pragma unroll
            for (int r = 0; r < 4; ++r)
                pden[slot * N_NODES + rb0 + t * 16 + quad * 4 + r] = accD[t][r];
        }
        #pragma unroll
        for (int r = 0; r < 4; ++r) {
            const int gi = rb0 + t * 16 + quad * 4 + r;
            float* np_ = pnum + ((size_t)slot * N_NODES + gi) * N_HID + m;
            np_[0]  = accN[t][0][r];
            np_[16] = accN[t][1][r];
            np_[32] = accN[t][2][r];
            np_[48] = accN[t][3][r];
        }
    }
}

// ---------------- Kernel 3: reduce j-chunks, divide, mean over heads (float4)
__global__ __launch_bounds__(256) void finalize_kernel(
    const float* __restrict__ pnum, const float* __restrict__ pden,
    float* __restrict__ out)
{
    const int idx = blockIdx.x * 256 + threadIdx.x;   // over N_NODES*16
    if (idx >= N_NODES * 16) return;
    const int i = idx >> 4;
    const int d4 = (idx & 15) * 4;
    float sx = 0.f, sy = 0.f, sz = 0.f, sw = 0.f;
    #pragma unroll
    for (int hh = 0; hh < N_HEADS; ++hh) {
        float nx = 0.f, ny = 0.f, nz = 0.f, nw_ = 0.f, ds = 0.f;
        #pragma unroll
        for (int jc = 0; jc < JS; ++jc) {
            const int slot = jc * N_HEADS + hh;
            const float4 v = *(const float4*)(pnum + ((size_t)slot * N_NODES + i) * N_HID + d4);
            nx += v.x; ny += v.y; nz += v.z; nw_ += v.w;
            ds += pden[slot * N_NODES + i];
        }
        const float r = 1.0f / ds;
        sx += nx * r; sy += ny * r; sz += nz * r; sw += nw_ * r;
    }
    float4 o; o.x = 0.25f * sx; o.y = 0.25f * sy; o.z = 0.25f * sz; o.w = 0.25f * sw;
    *(float4*)(out + (size_t)i * N_HID + d4) = o;
}

extern "C" void kernel_launch(void* const* d_in, const int* in_sizes, int n_in,
                              void* d_out, int out_size, void* d_ws, size_t ws_size,
                              hipStream_t stream)
{
    const float* h   = (const float*)d_in[0];
    const int*   adj = (const int*)d_in[1];
    const float* W   = (const float*)d_in[2];
    const float* a   = (const float*)d_in[3];
    float* out = (float*)d_out;

    char* ws = (char*)d_ws;
    short* htF = (short*)ws;
    size_t off = (size_t)N_HEADS * N_HID * N_NODES * 2;              // 3.1 MB
    float* srcv = (float*)(ws + off);        off += (size_t)N_HEADS * N_NODES * 4;
    unsigned* tE1pk = (unsigned*)(ws + off); off += (size_t)N_HEADS * (N_NODES/2) * 4;
    unsigned* tE2pk = (unsigned*)(ws + off); off += (size_t)N_HEADS * (N_NODES/2) * 4;
    float* pnum = (float*)(ws + off);        off += (size_t)JS * N_HEADS * N_NODES * N_HID * 4;  // 50.3 MB
    float* pden = (float*)(ws + off);

    ht_gemm_kernel<<<dim3(N_NODES / 32, N_HEADS), 256, 0, stream>>>(h, W, a, htF, srcv, tE1pk, tE2pk);
    gat_main_kernel<<<768, dim3(64, 4), 0, stream>>>(
        adj, htF, srcv, tE1pk, tE2pk, pnum, pden);
    finalize_kernel<<<dim3((N_NODES * 16 + 255) / 256), 256, 0, stream>>>(pnum, pden, out);
}

// Round 17
// 270.986 us; speedup vs baseline: 2.4365x; 1.0016x over previous
//
#include <hip/hip_runtime.h>
#include <hip/hip_bf16.h>

#define N_NODES 6144
#define IN_F 256
#define N_HEADS 4
#define N_HID 64
#define JS 8
#define JLEN (N_NODES / JS)        // 768
#define NW (JLEN / 32)             // 24 iterations per chunk row
#define SMB 776                    // byte stride per row: 768 + 8 (u64-aligned)

typedef __attribute__((ext_vector_type(4))) float floatx4;
typedef _Float16 half2_t __attribute__((ext_vector_type(2)));
typedef _Float16 half8_t __attribute__((ext_vector_type(8)));
typedef __attribute__((ext_vector_type(4))) unsigned uint4_t;

// ---------------- Kernel 1: ht = h @ W (fp32); epilogue -> htF (f16 MFMA B-fragment layout),
//   srcv (f32), tE1pk/tE2pk = f16x2 pairs of exp(tgt), exp(0.2*tgt).
__global__ __launch_bounds__(256) void ht_gemm_kernel(
    const float* __restrict__ h, const float* __restrict__ W,
    const float* __restrict__ a, short* __restrict__ htF,
    float* __restrict__ srcv, unsigned* __restrict__ tE1pk, unsigned* __restrict__ tE2pk)
{
    __shared__ float As[32][34];
    __shared__ float Bs[32][68];
    __shared__ float redS[32][16];
    __shared__ float redT[32][16];
    __shared__ unsigned short eh1[32], eh2[32];

    const int head = blockIdx.y;
    const int i0 = blockIdx.x * 32;
    const int tid = threadIdx.x;
    const int tx = tid & 15, ty = tid >> 4;

    float acc[2][4] = {};

    for (int k0 = 0; k0 < IN_F; k0 += 32) {
        __syncthreads();
        {
            const int m = tid >> 3, kq = tid & 7;
            const float4 v = *(const float4*)(h + (i0 + m) * IN_F + k0 + kq * 4);
            As[kq*4+0][m] = v.x; As[kq*4+1][m] = v.y;
            As[kq*4+2][m] = v.z; As[kq*4+3][m] = v.w;
        }
        #pragma unroll
        for (int it = 0; it < 2; ++it) {
            int l = it * 256 + tid;
            int k = l >> 4, nq = l & 15;
            *(float4*)&Bs[k][nq*4] = *(const float4*)(W + (k0 + k) * 256 + head * 64 + nq * 4);
        }
        __syncthreads();
        #pragma unroll
        for (int kk = 0; kk < 32; ++kk) {
            const float2 av = *(const float2*)&As[kk][ty*2];
            const float4 bv = *(const float4*)&Bs[kk][tx*4];
            const float aa[2] = {av.x, av.y};
            const float bb[4] = {bv.x, bv.y, bv.z, bv.w};
            #pragma unroll
            for (int r = 0; r < 2; ++r)
                #pragma unroll
                for (int c = 0; c < 4; ++c)
                    acc[r][c] = fmaf(aa[r], bb[c], acc[r][c]);
        }
    }

    #pragma unroll
    for (int r = 0; r < 2; ++r)
        #pragma unroll
        for (int c2 = 0; c2 < 4; ++c2) {
            const int d = tx * 4 + c2;
            const int j = i0 + ty * 2 + r;
            const int jt = j >> 5, q = (j >> 3) & 3, u = j & 7;
            const int c = d >> 4, n = d & 15;
            const size_t F = (((((size_t)head * 192 + jt) * 4 + c) * 16 + n) * 4 + q) * 8 + u;
            const _Float16 hv = (_Float16)acc[r][c2];
            htF[F] = *(const short*)&hv;
        }

    float as_[4], at_[4];
    #pragma unroll
    for (int c = 0; c < 4; ++c) {
        as_[c] = a[head * 128 + tx * 4 + c];
        at_[c] = a[head * 128 + 64 + tx * 4 + c];
    }
    #pragma unroll
    for (int r = 0; r < 2; ++r) {
        float ps = 0.f, pt = 0.f;
        #pragma unroll
        for (int c = 0; c < 4; ++c) {
            ps = fmaf(acc[r][c], as_[c], ps);
            pt = fmaf(acc[r][c], at_[c], pt);
        }
        redS[ty*2+r][tx] = ps;
        redT[ty*2+r][tx] = pt;
    }
    __syncthreads();
    if (tid < 64) {
        const int row = tid & 31;
        const float* src = (tid < 32) ? &redS[row][0] : &redT[row][0];
        float s = 0.f;
        #pragma unroll
        for (int x = 0; x < 16; ++x) s += src[x];
        if (tid < 32) {
            srcv[head * N_NODES + i0 + row] = s;
        } else {
            const _Float16 E1 = (_Float16)__expf(s);
            const _Float16 E2 = (_Float16)__expf(0.2f * s);
            eh1[row] = *(const unsigned short*)&E1;
            eh2[row] = *(const unsigned short*)&E2;
        }
    }
    __syncthreads();
    if (tid < 16) {
        const unsigned v1 = (unsigned)eh1[2*tid] | ((unsigned)eh1[2*tid+1] << 16);
        const unsigned v2 = (unsigned)eh2[2*tid] | ((unsigned)eh2[2*tid+1] << 16);
        tE1pk[head * (N_NODES/2) + i0/2 + tid] = v1;
        tE2pk[head * (N_NODES/2) + i0/2 + tid] = v2;
    }
}

// ---------------- Kernel 2: fused adj->byte-mask + masked rank-1 softmax + PV.
// R15 base + WAVE DESYNC: wave h starts its j-loop at iteration h*6 (mod 24) so the
// 4 waves of a block stall on memory at different phases instead of convoying.
// launch_bounds(256,3) fixed -- (256,6) spills accumulators (R13: 2GB scratch).
__global__ __launch_bounds__(256, 3) void gat_main_kernel(
    const int* __restrict__ adj, const short* __restrict__ htF,
    const float* __restrict__ srcv, const unsigned* __restrict__ tE1pk,
    const unsigned* __restrict__ tE2pk,
    float* __restrict__ pnum, float* __restrict__ pden)
{
    __shared__ unsigned char smaskB[64 * SMB];   // 48.5 KB byte-mask (0x00/0xFF per j)

    const int bid = blockIdx.x;
    const int xcd = bid & 7;
    const int idx = bid >> 3;
    const int jc = idx / 12;
    const int rb0 = ((idx % 12) * 8 + xcd) * 64;

    const int lane = threadIdx.x;
    const int head = threadIdx.y;                // wave = head
    const int m = lane & 15, quad = lane >> 4;
    const int jbase = jc * JLEN;

    // ---- dense staging: item = (row r, 256-j group cg); lane l covers j = cg*256 + l*4..+3.
    const int* adjb = adj + (size_t)rb0 * N_NODES + jbase + lane * 4;
    for (int k0 = 0; k0 < 48; k0 += 8) {
        int4 v[8];
        #pragma unroll
        for (int s = 0; s < 8; ++s) {
            const int item = (k0 + s) * 4 + head;    // 0..191
            const int r = item & 63, cg = item >> 6; // 64 rows x 3 groups
            v[s] = *(const int4*)(adjb + (size_t)r * N_NODES + cg * 256);
        }
        #pragma unroll
        for (int s = 0; s < 8; ++s) {
            const int item = (k0 + s) * 4 + head;
            const int r = item & 63, cg = item >> 6;
            const unsigned b = (unsigned)(v[s].x | (v[s].y << 8) | (v[s].z << 16) | (v[s].w << 24)) * 255u;
            *(unsigned*)(smaskB + r * SMB + cg * 256 + lane * 4) = b;
        }
    }
    __syncthreads();

    half2_t e1s[4], e2s[4];
    #pragma unroll
    for (int t = 0; t < 4; ++t) {
        const float sv = srcv[head * N_NODES + rb0 + t * 16 + m];
        const _Float16 a1 = (_Float16)__expf(sv);
        const _Float16 a2 = (_Float16)__expf(0.2f * sv);
        e1s[t] = (half2_t){a1, a1};
        e2s[t] = (half2_t){a2, a2};
    }

    const short* fb = htF + ((size_t)(head * 192 + (jbase >> 5)) * 4) * 512 + (m * 4 + quad) * 8;
    const unsigned char* mrow = smaskB + m * SMB + quad * 8;   // + t*16*SMB + w*32
    const unsigned* pe1 = tE1pk + head * (N_NODES/2) + (jbase >> 1);
    const unsigned* pe2 = tE2pk + head * (N_NODES/2) + (jbase >> 1);

    half8_t bones;
    #pragma unroll
    for (int u = 0; u < 8; ++u) bones[u] = (_Float16)1.0f;

    floatx4 accN[4][4];
    floatx4 accD[4];
    #pragma unroll
    for (int t = 0; t < 4; ++t) {
        accD[t] = (floatx4){0,0,0,0};
        #pragma unroll
        for (int c = 0; c < 4; ++c) accN[t][c] = (floatx4){0,0,0,0};
    }

    // ---- wave desync: wave h's schedule is w_eff = (w + h*6) mod 24
    const int wshift = head * 6;

    // depth-1 prefetch for first effective iteration
    half8_t bn[4];
    #pragma unroll
    for (int c = 0; c < 4; ++c)
        bn[c] = *(const half8_t*)(fb + (size_t)wshift * 2048 + c * 512);
    uint4_t E1n = *(const uint4_t*)(pe1 + wshift * 16 + quad * 4);
    uint4_t E2n = *(const uint4_t*)(pe2 + wshift * 16 + quad * 4);

    for (int w = 0; w < NW; ++w) {
        int weff = w + wshift;      if (weff >= NW) weff -= NW;
        int wn   = w + 1 + wshift;  if (wn >= NW)   wn -= NW;   // wraps; tail load unused

        half8_t bc[4];
        #pragma unroll
        for (int c = 0; c < 4; ++c) bc[c] = bn[c];
        const uint4_t E1 = E1n, E2 = E2n;

        #pragma unroll
        for (int c = 0; c < 4; ++c)
            bn[c] = *(const half8_t*)(fb + (size_t)wn * 2048 + c * 512);
        E1n = *(const uint4_t*)(pe1 + wn * 16 + quad * 4);
        E2n = *(const uint4_t*)(pe2 + wn * 16 + quad * 4);

        const unsigned E1a[4] = {E1.x, E1.y, E1.z, E1.w};
        const unsigned E2a[4] = {E2.x, E2.y, E2.z, E2.w};

        #pragma unroll
        for (int t = 0; t < 4; ++t) {
            // byte-mask u64 for this row-tile's 8 j; expand to halfword masks via v_perm
            const unsigned long long mB =
                *(const unsigned long long*)(mrow + t * (16*SMB) + weff * 32);
            const unsigned mlo = (unsigned)mB, mhi = (unsigned)(mB >> 32);
            const unsigned k0 = __builtin_amdgcn_perm(0u, mlo, 0x01010000u);  // u0,u1
            const unsigned k1 = __builtin_amdgcn_perm(0u, mlo, 0x03030202u);  // u2,u3
            const unsigned k2 = __builtin_amdgcn_perm(0u, mhi, 0x01010000u);  // u4,u5
            const unsigned k3 = __builtin_amdgcn_perm(0u, mhi, 0x03030202u);  // u6,u7
            const unsigned ka[4] = {k0, k1, k2, k3};

            uint4_t af_u;
            #pragma unroll
            for (int p = 0; p < 4; ++p) {
                const half2_t p1 = __builtin_bit_cast(half2_t, E1a[p]) * e1s[t];
                const half2_t p2 = __builtin_bit_cast(half2_t, E2a[p]) * e2s[t];
                const half2_t mx = __builtin_elementwise_max(p1, p2); // exp(lrelu) = max of exps
                const unsigned r = __builtin_bit_cast(unsigned, mx) & ka[p];
                if (p == 0) af_u.x = r; else if (p == 1) af_u.y = r;
                else if (p == 2) af_u.z = r; else af_u.w = r;
            }
            const half8_t af = __builtin_bit_cast(half8_t, af_u);
            #pragma unroll
            for (int c = 0; c < 4; ++c)
                accN[t][c] = __builtin_amdgcn_mfma_f32_16x16x32_f16(af, bc[c], accN[t][c], 0, 0, 0);
            accD[t] = __builtin_amdgcn_mfma_f32_16x16x32_f16(af, bones, accD[t], 0, 0, 0);
        }
    }

    const int slot = jc * N_HEADS + head;
    #pragma unroll
    for (int t = 0; t < 4; ++t) {
        if (m == 0) {
            #pragma unroll
            for (int r = 0; r < 4; ++r)
                pden[slot * N_NODES + rb0 + t * 16 + quad * 4 + r] = accD[t][r];
        }
        #pragma unroll
        for (int r = 0; r < 4; ++r) {
            const int gi = rb0 + t * 16 + quad * 4 + r;
            float* np_ = pnum + ((size_t)slot * N_NODES + gi) * N_HID + m;
            np_[0]  = accN[t][0][r];
            np_[16] = accN[t][1][r];
            np_[32] = accN[t][2][r];
            np_[48] = accN[t][3][r];
        }
    }
}

// ---------------- Kernel 3: reduce j-chunks, divide, mean over heads (float4)
__global__ __launch_bounds__(256) void finalize_kernel(
    const float* __restrict__ pnum, const float* __restrict__ pden,
    float* __restrict__ out)
{
    const int idx = blockIdx.x * 256 + threadIdx.x;   // over N_NODES*16
    if (idx >= N_NODES * 16) return;
    const int i = idx >> 4;
    const int d4 = (idx & 15) * 4;
    float sx = 0.f, sy = 0.f, sz = 0.f, sw = 0.f;
    #pragma unroll
    for (int hh = 0; hh < N_HEADS; ++hh) {
        float nx = 0.f, ny = 0.f, nz = 0.f, nw_ = 0.f, ds = 0.f;
        #pragma unroll
        for (int jc = 0; jc < JS; ++jc) {
            const int slot = jc * N_HEADS + hh;
            const float4 v = *(const float4*)(pnum + ((size_t)slot * N_NODES + i) * N_HID + d4);
            nx += v.x; ny += v.y; nz += v.z; nw_ += v.w;
            ds += pden[slot * N_NODES + i];
        }
        const float r = 1.0f / ds;
        sx += nx * r; sy += ny * r; sz += nz * r; sw += nw_ * r;
    }
    float4 o; o.x = 0.25f * sx; o.y = 0.25f * sy; o.z = 0.25f * sz; o.w = 0.25f * sw;
    *(float4*)(out + (size_t)i * N_HID + d4) = o;
}

extern "C" void kernel_launch(void* const* d_in, const int* in_sizes, int n_in,
                              void* d_out, int out_size, void* d_ws, size_t ws_size,
                              hipStream_t stream)
{
    const float* h   = (const float*)d_in[0];
    const int*   adj = (const int*)d_in[1];
    const float* W   = (const float*)d_in[2];
    const float* a   = (const float*)d_in[3];
    float* out = (float*)d_out;

    char* ws = (char*)d_ws;
    short* htF = (short*)ws;
    size_t off = (size_t)N_HEADS * N_HID * N_NODES * 2;              // 3.1 MB
    float* srcv = (float*)(ws + off);        off += (size_t)N_HEADS * N_NODES * 4;
    unsigned* tE1pk = (unsigned*)(ws + off); off += (size_t)N_HEADS * (N_NODES/2) * 4;
    unsigned* tE2pk = (unsigned*)(ws + off); off += (size_t)N_HEADS * (N_NODES/2) * 4;
    float* pnum = (float*)(ws + off);        off += (size_t)JS * N_HEADS * N_NODES * N_HID * 4;  // 50.3 MB
    float* pden = (float*)(ws + off);

    ht_gemm_kernel<<<dim3(N_NODES / 32, N_HEADS), 256, 0, stream>>>(h, W, a, htF, srcv, tE1pk, tE2pk);
    gat_main_kernel<<<768, dim3(64, 4), 0, stream>>>(
        adj, htF, srcv, tE1pk, tE2pk, pnum, pden);
    finalize_kernel<<<dim3((N_NODES * 16 + 255) / 256), 256, 0, stream>>>(pnum, pden, out);
}